// Round 1
// baseline (248.367 us; speedup 1.0000x reference)
//
#include <hip/hip_runtime.h>
#include <math.h>

#define H 256
#define EPS 1e-4f

__device__ inline float2 wave_reduce_sum2(float a, float b) {
    #pragma unroll
    for (int off = 32; off >= 1; off >>= 1) {
        a += __shfl_xor(a, off);
        b += __shfl_xor(b, off);
    }
    return make_float2(a, b);
}

// One wave (64 lanes) per batch. Levinson-Durbin solve of the symmetric
// Toeplitz system A v = b, A[j,k] = r[|j-k|] + eps*delta_jk.
__global__ __launch_bounds__(64) void awloss_batch(
        const float* __restrict__ recon,
        const float* __restrict__ target,
        float* __restrict__ losses) {
    const int b    = blockIdx.x;
    const int lane = threadIdx.x;

    __shared__ float tgt[H], rec[H], rho[H], bb[H], xs[H], ys[H];

    const float* trow = target + b * H;
    const float* rrow = recon  + b * H;
    #pragma unroll
    for (int c = 0; c < 4; ++c) {
        int i = c * 64 + lane;
        tgt[i] = trow[i];
        rec[i] = rrow[i];
    }
    __syncthreads();

    // --- autocorrelation r[d] and RHS b[j] (cross-correlation) ---
    float racc[4] = {0.f, 0.f, 0.f, 0.f};
    float bacc[4] = {0.f, 0.f, 0.f, 0.f};
    for (int m = 0; m < H; ++m) {
        float tm = tgt[m];               // broadcast read
        #pragma unroll
        for (int c = 0; c < 4; ++c) {
            int d  = c * 64 + lane;      // lane-stride-1 -> conflict-free
            int md = m + d;
            if (md < H) racc[c] += tm * tgt[md];
            int rj = m + d - 127;        // pad_l = (h-1)/2 = 127
            if (rj >= 0 && rj < H) bacc[c] += tm * rec[rj];
        }
    }
    #pragma unroll
    for (int c = 0; c < 4; ++c) {
        int d = c * 64 + lane;
        rho[d] = racc[c];
        bb[d]  = bacc[c];
    }
    __syncthreads();

    // normalize to unit diagonal
    float t0 = rho[0] + EPS;
    float inv_t0 = 1.0f / t0;
    #pragma unroll
    for (int c = 0; c < 4; ++c) {
        int d = c * 64 + lane;
        float rv = rho[d] * inv_t0;
        rho[d] = (d == 0) ? 1.0f : rv;
        bb[d] *= inv_t0;
    }
    __syncthreads();

    // --- Levinson recursion (all lanes redundantly hold scalars) ---
    float alpha = -rho[1];
    float beta  = 1.0f;
    if (lane == 0) { xs[0] = bb[0]; ys[0] = -rho[1]; }
    // single wave: DS ops are wave-ordered; program-order read-before-write
    // guarantees correctness without barriers inside the loop.

    for (int k = 1; k < H; ++k) {
        beta *= (1.0f - alpha * alpha);

        float dxv = 0.f, dyv = 0.f;
        float yrev[4];
        #pragma unroll
        for (int c = 0; c < 4; ++c) {
            int i = c * 64 + lane;
            bool p = (i < k);
            float rv = p ? rho[i + 1]    : 0.f;
            float xv = p ? xs[k - 1 - i] : 0.f;
            float yv = p ? ys[k - 1 - i] : 0.f;
            yrev[c] = yv;
            dxv += rv * xv;
            dyv += rv * yv;
        }
        float2 dd = wave_reduce_sum2(dxv, dyv);

        float ib   = 1.0f / beta;
        float mu   = (bb[k] - dd.x) * ib;
        bool  last = (k == H - 1);
        float anew = last ? 0.f : -(rho[k + 1] + dd.y) * ib;

        float yold[4];
        #pragma unroll
        for (int c = 0; c < 4; ++c) {
            int i = c * 64 + lane;
            yold[c] = (i < k) ? ys[i] : 0.f;
        }
        #pragma unroll
        for (int c = 0; c < 4; ++c) {
            int i = c * 64 + lane;
            if (i < k) {
                xs[i] += mu * yrev[c];
                if (!last) ys[i] = yold[c] + anew * yrev[c];
            }
        }
        if (lane == 0) {
            xs[k] = mu;
            if (!last) ys[k] = anew;
        }
        alpha = anew;
    }

    // --- loss: 0.5 * sqrt(sum((T*v)^2) / sum(v^2)) ---
    float sT = 0.f, sV = 0.f;
    const float dx = 20.0f / 255.0f;
    #pragma unroll
    for (int c = 0; c < 4; ++c) {
        int i = c * 64 + lane;
        float v  = xs[i];
        float u  = -10.0f + dx * (float)i + 0.5f * dx;
        float Ti = 1.0f - expf(-0.5f * u * u);   // normalizers == 1.0f in f32
        float tv = Ti * v;
        sT += tv * tv;
        sV += v * v;
    }
    float2 ss = wave_reduce_sum2(sT, sV);
    if (lane == 0) losses[b] = 0.5f * sqrtf(ss.x / ss.y);
}

// deterministic final reduction of 512 per-batch losses
__global__ __launch_bounds__(64) void awloss_reduce(
        const float* __restrict__ losses, float* __restrict__ out) {
    int lane = threadIdx.x;
    float s = 0.f;
    #pragma unroll
    for (int c = 0; c < 8; ++c) s += losses[c * 64 + lane];
    #pragma unroll
    for (int off = 32; off >= 1; off >>= 1) s += __shfl_xor(s, off);
    if (lane == 0) out[0] = s;
}

extern "C" void kernel_launch(void* const* d_in, const int* in_sizes, int n_in,
                              void* d_out, int out_size, void* d_ws, size_t ws_size,
                              hipStream_t stream) {
    const float* recon  = (const float*)d_in[0];
    const float* target = (const float*)d_in[1];
    float* losses = (float*)d_ws;   // 512 floats
    float* out    = (float*)d_out;

    awloss_batch<<<512, 64, 0, stream>>>(recon, target, losses);
    awloss_reduce<<<1, 64, 0, stream>>>(losses, out);
}

// Round 2
// 129.101 us; speedup vs baseline: 1.9238x; 1.9238x over previous
//
#include <hip/hip_runtime.h>
#include <math.h>

#define H 256
#define EPS 1e-4f

// ---- DPP helpers (gfx9/CDNA) ----
// mov_dpp with 0-fill for invalid source lanes (bound_ctrl:0 semantics)
template <int CTRL>
__device__ __forceinline__ float dpp_mov0(float x) {
    return __int_as_float(
        __builtin_amdgcn_update_dpp(0, __float_as_int(x), CTRL, 0xf, 0xf, true));
}

__device__ __forceinline__ float rdlane63(float x) {
    return __int_as_float(__builtin_amdgcn_readlane(__float_as_int(x), 63));
}

// full-wave sum of two values; result broadcast (uniform) in both.
// classic gfx9 sequence: row_shr:1,2,4,8 then row_bcast:15, row_bcast:31,
// total lands in lane 63.
__device__ __forceinline__ void wave_red_sum2(float& a, float& b) {
    a += dpp_mov0<0x111>(a);  b += dpp_mov0<0x111>(b);   // row_shr:1
    a += dpp_mov0<0x112>(a);  b += dpp_mov0<0x112>(b);   // row_shr:2
    a += dpp_mov0<0x114>(a);  b += dpp_mov0<0x114>(b);   // row_shr:4
    a += dpp_mov0<0x118>(a);  b += dpp_mov0<0x118>(b);   // row_shr:8
    a += dpp_mov0<0x142>(a);  b += dpp_mov0<0x142>(b);   // row_bcast:15
    a += dpp_mov0<0x143>(a);  b += dpp_mov0<0x143>(b);   // row_bcast:31
    a = rdlane63(a);
    b = rdlane63(b);
}

__device__ __forceinline__ float frcp(float v) {
    float r = __builtin_amdgcn_rcpf(v);
    r = fmaf(r, fmaf(-v, r, 1.0f), r);   // one Newton step -> ~1 ulp
    return r;
}

// One wave (64 lanes) per batch. Levinson-Durbin for symmetric Toeplitz
// A v = b, A[j,k] = r[|j-k|] + eps*delta. Fully register-resident:
// lane-major layout, element e = lane*4 + c. Maintains x, y AND their
// reversals u, w so all updates are elementwise + one wave_shr:1 DPP.
__global__ __launch_bounds__(64) void awloss_batch(
        const float* __restrict__ recon,
        const float* __restrict__ target,
        float* __restrict__ losses) {
    const int b    = blockIdx.x;
    const int lane = threadIdx.x;

    __shared__ float tgt[H], rec[H], rho_s[H + 4], bb_s[H];

    const float* trow = target + b * H;
    const float* rrow = recon  + b * H;
    #pragma unroll
    for (int c = 0; c < 4; ++c) {
        int i = c * 64 + lane;
        tgt[i] = trow[i];
        rec[i] = rrow[i];
    }
    if (lane < 4) rho_s[H + lane] = 0.f;   // pad so rho_s[k+1] at k=255 reads 0
    __syncthreads();

    // --- autocorrelation r[d], cross-correlation b[j]  (chunk-major: d=c*64+lane,
    //     consecutive lanes -> conflict-free LDS) ---
    float racc[4] = {0.f, 0.f, 0.f, 0.f};
    float bacc[4] = {0.f, 0.f, 0.f, 0.f};
    #pragma unroll 4
    for (int m = 0; m < H; ++m) {
        float tm = tgt[m];               // broadcast
        #pragma unroll
        for (int c = 0; c < 4; ++c) {
            int d  = c * 64 + lane;
            int md = m + d;
            if (md < H) racc[c] += tm * tgt[md];
            int rj = m + d - 127;        // pad_l = (h-1)/2 = 127
            if (rj >= 0 && rj < H) bacc[c] += tm * rec[rj];
        }
    }
    // normalize to unit diagonal; write rho, bb to LDS (for uniform broadcasts
    // and the lane-major reload)
    float t0 = __int_as_float(__builtin_amdgcn_readlane(__float_as_int(racc[0]), 0)) + EPS;
    float inv_t0 = frcp(t0);
    #pragma unroll
    for (int c = 0; c < 4; ++c) {
        int d = c * 64 + lane;
        rho_s[d] = (d == 0) ? 1.0f : racc[c] * inv_t0;
        bb_s[d]  = bacc[c] * inv_t0;
    }
    __syncthreads();

    // --- register state, lane-major (e = lane*4 + c) ---
    float rs[4];                         // rs[c] = rho[e+1]
    #pragma unroll
    for (int c = 0; c < 4; ++c) rs[c] = rho_s[lane * 4 + c + 1];

    float alpha = -rho_s[1];             // uniform broadcast
    float bb0   = bb_s[0];
    float x[4] = {0.f,0.f,0.f,0.f}, y[4] = {0.f,0.f,0.f,0.f};
    float u[4] = {0.f,0.f,0.f,0.f}, w[4] = {0.f,0.f,0.f,0.f};
    if (lane == 0) { x[0] = bb0; u[0] = bb0; y[0] = alpha; w[0] = alpha; }
    const bool l0 = (lane == 0);
    const int  e0 = lane * 4;
    float beta = 1.0f;

    for (int k = 1; k < H; ++k) {
        // uniform broadcast loads, issued early, consumed after the reduce
        float bbk = bb_s[k];
        float rk1 = rho_s[k + 1];

        beta = beta * (1.0f - alpha * alpha);

        // dx = sum rho[i+1]*x[k-1-i] = <rs, u>;  dy = <rs, w>
        float dx = rs[3] * u[3];
        float dy = rs[3] * w[3];
        dx = fmaf(rs[2], u[2], dx);  dy = fmaf(rs[2], w[2], dy);
        dx = fmaf(rs[1], u[1], dx);  dy = fmaf(rs[1], w[1], dy);
        dx = fmaf(rs[0], u[0], dx);  dy = fmaf(rs[0], w[0], dy);
        wave_red_sum2(dx, dy);

        float ib   = frcp(beta);
        float mu   = (bbk - dx) * ib;
        bool  last = (k == H - 1);
        float a    = last ? 0.f : (-(rk1 + dy) * ib);

        // elementwise updates (entries >= current length are 0 and stay 0)
        float t1[4], t2[4], t3[4];
        #pragma unroll
        for (int c = 0; c < 4; ++c) {
            t1[c] = fmaf(a,  w[c], y[c]);   // new y (pre-insert)
            t2[c] = fmaf(a,  y[c], w[c]);   // shift -> new w
            t3[c] = fmaf(mu, y[c], u[c]);   // shift -> new u
            x[c]  = fmaf(mu, w[c], x[c]);
        }
        // insert x[k]=mu, y[k]=a at element k
        #pragma unroll
        for (int c = 0; c < 4; ++c) {
            bool ins = (e0 + c == k);
            x[c] = ins ? mu : x[c];
            y[c] = ins ? a  : t1[c];
        }
        // shift-by-one-element: within-lane rename + one wave_shr:1 DPP for the
        // lane boundary; insert at element 0
        float ubnd = dpp_mov0<0x138>(t3[3]);   // wave_shr:1
        float wbnd = dpp_mov0<0x138>(t2[3]);
        u[3] = t3[2]; u[2] = t3[1]; u[1] = t3[0]; u[0] = l0 ? mu : ubnd;
        w[3] = t2[2]; w[2] = t2[1]; w[1] = t2[0]; w[0] = l0 ? a  : wbnd;

        alpha = a;
    }

    // --- loss: 0.5*sqrt(sum((T*v)^2)/sum(v^2)) ---
    float sT = 0.f, sV = 0.f;
    const float dxg = 20.0f / 255.0f;
    #pragma unroll
    for (int c = 0; c < 4; ++c) {
        float v  = x[c];
        float uc = -10.0f + dxg * (float)(e0 + c) + 0.5f * dxg;
        float Ti = 1.0f - expf(-0.5f * uc * uc);   // normalizers == 1.0f in f32
        float tv = Ti * v;
        sT += tv * tv;
        sV += v * v;
    }
    wave_red_sum2(sT, sV);
    if (lane == 0) losses[b] = 0.5f * sqrtf(sT / sV);
}

// deterministic final reduction of 512 per-batch losses
__global__ __launch_bounds__(64) void awloss_reduce(
        const float* __restrict__ losses, float* __restrict__ out) {
    int lane = threadIdx.x;
    float s = 0.f;
    #pragma unroll
    for (int c = 0; c < 8; ++c) s += losses[c * 64 + lane];
    float d = 0.f;
    wave_red_sum2(s, d);
    if (lane == 0) out[0] = s;
}

extern "C" void kernel_launch(void* const* d_in, const int* in_sizes, int n_in,
                              void* d_out, int out_size, void* d_ws, size_t ws_size,
                              hipStream_t stream) {
    const float* recon  = (const float*)d_in[0];
    const float* target = (const float*)d_in[1];
    float* losses = (float*)d_ws;   // 512 floats
    float* out    = (float*)d_out;

    awloss_batch<<<512, 64, 0, stream>>>(recon, target, losses);
    awloss_reduce<<<1, 64, 0, stream>>>(losses, out);
}

// Round 3
// 35.571 us; speedup vs baseline: 6.9823x; 3.6294x over previous
//
#include <hip/hip_runtime.h>
#include <math.h>

#define H 256
#define EPS 1e-4f

// ---- DPP helpers (gfx9/CDNA), bound_ctrl:0 (0-fill invalid lanes) ----
template <int CTRL>
__device__ __forceinline__ float dpp0(float x) {
    return __int_as_float(
        __builtin_amdgcn_update_dpp(0, __float_as_int(x), CTRL, 0xf, 0xf, true));
}
__device__ __forceinline__ float rdlane(float x, int l) {
    return __int_as_float(__builtin_amdgcn_readlane(__float_as_int(x), l));
}
__device__ __forceinline__ float frcp_fast(float v) {   // ~1e-7 rel, no Newton
    return __builtin_amdgcn_rcpf(v);
}
__device__ __forceinline__ float frcp_nr(float v) {     // + one Newton step
    float r = __builtin_amdgcn_rcpf(v);
    return fmaf(r, fmaf(-v, r, 1.0f), r);
}
// full-wave sum of two values, result uniform (row_shr cascade + bcast + readlane)
__device__ __forceinline__ void wave_red_sum2(float& a, float& b) {
    a += dpp0<0x111>(a);  b += dpp0<0x111>(b);
    a += dpp0<0x112>(a);  b += dpp0<0x112>(b);
    a += dpp0<0x114>(a);  b += dpp0<0x114>(b);
    a += dpp0<0x118>(a);  b += dpp0<0x118>(b);
    a += dpp0<0x142>(a);  b += dpp0<0x142>(b);
    a += dpp0<0x143>(a);  b += dpp0<0x143>(b);
    a = rdlane(a, 63);
    b = rdlane(b, 63);
}

// One Schur-algorithm step k -> k+1.  KB = k&3, KR = (k+1)&3 must be literals.
// Sequences lane-major: element e = 4*lane + c (register index c).
// gamma = -F[k+1]/B[k];  B' = sh1(B)+g*F;  F' = F+g*sh1(B);
// ra' = sh1(ra)+g*a;     a' = a+g*sh1(ra);
// mu = R[k+1]/B'[k+1];   x' = x+mu*ra';    R' = R-mu*B'.
#define STEP(kk, KB, KR) do {                                            \
    const int lF = ((kk) + 1) >> 2;                                      \
    const int lB = (kk) >> 2;                                            \
    float sF = rdlane(F[KR], lF);                                        \
    float sB = rdlane(B[KB], lB);                                        \
    float g  = -sF * frcp_fast(sB);                                      \
    float sb0 = dpp0<0x138>(B[3]);            /* wave_shr:1 */           \
    float nB0 = fmaf(g, F[0], sb0);                                      \
    float nB1 = fmaf(g, F[1], B[0]);                                     \
    float nB2 = fmaf(g, F[2], B[1]);                                     \
    float nB3 = fmaf(g, F[3], B[2]);                                     \
    float nF0 = fmaf(g, sb0,  F[0]);                                     \
    float nF1 = fmaf(g, B[0], F[1]);                                     \
    float nF2 = fmaf(g, B[1], F[2]);                                     \
    float nF3 = fmaf(g, B[2], F[3]);                                     \
    float sr0 = dpp0<0x138>(ra[3]);                                      \
    float nr0 = fmaf(g, a[0], sr0);                                      \
    float nr1 = fmaf(g, a[1], ra[0]);                                    \
    float nr2 = fmaf(g, a[2], ra[1]);                                    \
    float nr3 = fmaf(g, a[3], ra[2]);                                    \
    float na0 = fmaf(g, sr0,   a[0]);                                    \
    float na1 = fmaf(g, ra[0], a[1]);                                    \
    float na2 = fmaf(g, ra[1], a[2]);                                    \
    float na3 = fmaf(g, ra[2], a[3]);                                    \
    float nBk[4] = {nB0, nB1, nB2, nB3};                                 \
    float sE = rdlane(nBk[KR], lF);           /* E_{k+1} = B'[k+1] */    \
    float sR = rdlane(R[KR], lF);                                        \
    float mu = sR * frcp_fast(sE);                                       \
    x[0] = fmaf(mu, nr0, x[0]);  R[0] = fmaf(-mu, nB0, R[0]);            \
    x[1] = fmaf(mu, nr1, x[1]);  R[1] = fmaf(-mu, nB1, R[1]);            \
    x[2] = fmaf(mu, nr2, x[2]);  R[2] = fmaf(-mu, nB2, R[2]);            \
    x[3] = fmaf(mu, nr3, x[3]);  R[3] = fmaf(-mu, nB3, R[3]);            \
    B[0] = nB0; B[1] = nB1; B[2] = nB2; B[3] = nB3;                      \
    F[0] = nF0; F[1] = nF1; F[2] = nF2; F[3] = nF3;                      \
    a[0] = na0; a[1] = na1; a[2] = na2; a[3] = na3;                      \
    ra[0] = nr0; ra[1] = nr1; ra[2] = nr2; ra[3] = nr3;                  \
} while (0)

// One wave per batch.  Schur solve of symmetric Toeplitz A v = b,
// A[j,k] = r[|j-k|] + eps*delta.
__global__ __launch_bounds__(64) void awloss_batch(
        const float* __restrict__ recon,
        const float* __restrict__ target,
        float* __restrict__ losses) {
    const int b    = blockIdx.x;
    const int lane = threadIdx.x;

    __shared__ __align__(16) float tgtp[2 * H];   // target padded with trailing zeros
    __shared__ __align__(16) float recp[2 * H];   // recon padded: [127..382] live

    const float* trow = target + b * H;
    const float* rrow = recon  + b * H;
    float tv[4], rv[4];
    #pragma unroll
    for (int c = 0; c < 4; ++c) {
        int i = c * 64 + lane;
        tv[c] = trow[i];
        rv[c] = rrow[i];
    }
    #pragma unroll
    for (int c = 0; c < 8; ++c) {
        int i = c * 64 + lane;
        tgtp[i] = 0.f;
        recp[i] = 0.f;
    }
    __syncthreads();
    #pragma unroll
    for (int c = 0; c < 4; ++c) {
        int i = c * 64 + lane;
        tgtp[i]       = tv[c];
        recp[127 + i] = rv[c];
    }
    __syncthreads();

    // --- autocorrelation r[d], RHS b[d] (chunk-major d = c*64+lane), no guards ---
    float racc[4] = {0.f, 0.f, 0.f, 0.f};
    float bacc[4] = {0.f, 0.f, 0.f, 0.f};
    #pragma unroll 4
    for (int m = 0; m < H; ++m) {
        float tm = tgtp[m];                       // uniform broadcast
        #pragma unroll
        for (int c = 0; c < 4; ++c) {
            int e = m + c * 64 + lane;
            racc[c] = fmaf(tm, tgtp[e], racc[c]); // r[d] += t[m]*t[m+d]
            bacc[c] = fmaf(tm, recp[e], bacc[c]); // b[d] += t[m]*rec[m+d-127]
        }
    }

    // normalize to unit diagonal; transpose chunk-major -> lane-major via LDS
    float t0  = rdlane(racc[0], 0) + EPS;
    float it0 = frcp_nr(t0);
    #pragma unroll
    for (int c = 0; c < 4; ++c) {
        int d = c * 64 + lane;
        tgtp[d]     = (d == 0) ? 1.0f : racc[c] * it0;  // rho
        tgtp[H + d] = bacc[c] * it0;                    // bb
    }
    __syncthreads();

    float F[4], B[4], R[4], x[4], a[4], ra[4];
    float4 rhov = *(const float4*)&tgtp[4 * lane];
    float4 bbv  = *(const float4*)&tgtp[H + 4 * lane];
    float rh[4] = {rhov.x, rhov.y, rhov.z, rhov.w};
    float bv[4] = {bbv.x,  bbv.y,  bbv.z,  bbv.w};

    float bb0 = rdlane(bv[0], 0);
    const bool l0 = (lane == 0);
    #pragma unroll
    for (int c = 0; c < 4; ++c) {
        F[c] = rh[c];                      // F_0[j] = rho[j]
        B[c] = rh[c];                      // B_0[j] = rho[j], B[0]=1
        R[c] = fmaf(-bb0, rh[c], bv[c]);   // R_0 = bb - bb0*rho
        x[c] = 0.f; a[c] = 0.f; ra[c] = 0.f;
    }
    if (l0) { x[0] = bb0; a[0] = 1.0f; ra[0] = 1.0f; }

    // --- Schur recursion: 255 steps, unrolled x4 for static register indices ---
    for (int t = 0; t < 63; ++t) {
        int k = 4 * t;
        STEP(k,     0, 1);
        STEP(k + 1, 1, 2);
        STEP(k + 2, 2, 3);
        STEP(k + 3, 3, 0);
    }
    STEP(252, 0, 1);
    STEP(253, 1, 2);
    STEP(254, 2, 3);

    // --- loss: 0.5*sqrt(sum((T*v)^2)/sum(v^2)), elements e = 4*lane+c ---
    float sT = 0.f, sV = 0.f;
    const float dxg = 20.0f / 255.0f;
    const int e0 = 4 * lane;
    #pragma unroll
    for (int c = 0; c < 4; ++c) {
        float v  = x[c];
        float u  = -10.0f + dxg * (float)(e0 + c) + 0.5f * dxg;
        float Ti = 1.0f - expf(-0.5f * u * u);   // T normalizers == 1.0f in f32
        float tw = Ti * v;
        sT += tw * tw;
        sV += v * v;
    }
    wave_red_sum2(sT, sV);
    if (l0) losses[b] = 0.5f * sqrtf(sT / sV);
}

// deterministic final reduction of 512 per-batch losses
__global__ __launch_bounds__(64) void awloss_reduce(
        const float* __restrict__ losses, float* __restrict__ out) {
    int lane = threadIdx.x;
    float s = 0.f;
    #pragma unroll
    for (int c = 0; c < 8; ++c) s += losses[c * 64 + lane];
    float d = 0.f;
    wave_red_sum2(s, d);
    if (lane == 0) out[0] = s;
}

extern "C" void kernel_launch(void* const* d_in, const int* in_sizes, int n_in,
                              void* d_out, int out_size, void* d_ws, size_t ws_size,
                              hipStream_t stream) {
    const float* recon  = (const float*)d_in[0];
    const float* target = (const float*)d_in[1];
    float* losses = (float*)d_ws;   // 512 floats
    float* out    = (float*)d_out;

    awloss_batch<<<512, 64, 0, stream>>>(recon, target, losses);
    awloss_reduce<<<1, 64, 0, stream>>>(losses, out);
}